// Round 5
// baseline (3092.154 us; speedup 1.0000x reference)
//
#include <hip/hip_runtime.h>

#define H 128
#define LN_EPS 1e-5f

typedef _Float16 half8 __attribute__((ext_vector_type(8)));
typedef float floatx4 __attribute__((ext_vector_type(4)));

__device__ __forceinline__ float silu_f(float x) { return x / (1.0f + __expf(-x)); }

// ---------------------------------------------------------------------------
// Counting sort of edges into 8 dst-buckets (bucket = dst / ceil(N/8)).
// Scratch layout in d_out (as int*): perm[E] | cnt[8] | base[8] | cursor[8]
// ---------------------------------------------------------------------------
__global__ void hist_kernel(const int* __restrict__ edst, int E, int bsz,
                            int* __restrict__ cnt)
{
    __shared__ int lc[8];
    if (threadIdx.x < 8) lc[threadIdx.x] = 0;
    __syncthreads();
    for (int e = blockIdx.x * blockDim.x + threadIdx.x; e < E;
         e += gridDim.x * blockDim.x)
        atomicAdd(&lc[edst[e] / bsz], 1);
    __syncthreads();
    if (threadIdx.x < 8) atomicAdd(&cnt[threadIdx.x], lc[threadIdx.x]);
}

__global__ void prefix_kernel(int* __restrict__ cnt)
{
    if (threadIdx.x == 0 && blockIdx.x == 0) {
        int s = 0;
        for (int i = 0; i < 8; i++) {
            cnt[8 + i]  = s;   // base
            cnt[16 + i] = s;   // cursor
            s += cnt[i];
        }
    }
}

__global__ void scatter_kernel(const int* __restrict__ edst, int E, int bsz,
                               int* __restrict__ cursor, int* __restrict__ perm)
{
    for (int e = blockIdx.x * blockDim.x + threadIdx.x; e < E;
         e += gridDim.x * blockDim.x) {
        int b = edst[e] / bsz;
        int p = atomicAdd(&cursor[b], 1);
        perm[p] = e;
    }
}

// ---------------------------------------------------------------------------
// Edge kernel (fp16 MFMA): grid (8 buckets, GY). Block = 256 thr = 4 waves,
// tile = 64 edges x 128 out. MLP1 K=304(pad 320), MLP2 K=128. Scatter-add
// bucketed so each XCD's atomics stay in its own L2.
// ---------------------------------------------------------------------------
__global__ void __launch_bounds__(256)
edge_mfma(const float* __restrict__ h,
          const int* __restrict__ perm, const int* __restrict__ cnt,
          const int* __restrict__ esrc, const int* __restrict__ edst,
          const int* __restrict__ erel, const int* __restrict__ ncol,
          const int* __restrict__ nrole,
          const float* __restrict__ rel_emb, const float* __restrict__ role_emb,
          const float* __restrict__ col_emb,
          const float* __restrict__ eW1, const float* __restrict__ eb1,
          const float* __restrict__ eW2, const float* __restrict__ eb2,
          float* __restrict__ agg)
{
    __shared__ _Float16 sA[64 * 40];    // [edge][k-slice 32], stride 40 (skew)
    __shared__ _Float16 sB[128 * 40];   // [n][k-slice 32], stride 40
    __shared__ _Float16 sY[64 * 136];   // [edge][128], stride 136 (skew)
    __shared__ int sSrc[64], sDst[64], sRel[64], sRS[64], sRD[64], sCS[64], sCD[64];
    __shared__ float sRelE[128], sRoleE[48], sColE[24];

    const int tid  = threadIdx.x;
    const int lane = tid & 63;
    const int wv   = tid >> 6;     // wave 0..3 -> edge strip 16*wv
    const int lm   = lane & 15;
    const int lh   = lane >> 4;

    if (tid < 128) sRelE[tid] = rel_emb[tid];
    if (tid < 48)  sRoleE[tid] = role_emb[tid];
    if (tid < 24)  sColE[tid] = col_emb[tid];

    const int bucket = blockIdx.x;
    const int bcount = cnt[bucket];
    const int bbase  = cnt[8 + bucket];

    for (int t = blockIdx.y; t * 64 < bcount; t += gridDim.y)
    {
        __syncthreads();   // protect LDS of previous tile

        if (tid < 64) {
            int idx   = t * 64 + tid;
            int valid = idx < bcount;
            int e = valid ? perm[bbase + idx] : perm[bbase];
            int s = esrc[e], d = edst[e], r = erel[e];
            sSrc[tid] = s; sRel[tid] = r;
            sRS[tid]  = nrole[s]; sRD[tid] = nrole[d];
            sCS[tid]  = ncol[s];  sCD[tid] = ncol[d];
            sDst[tid] = valid ? d : -1;
        }

        floatx4 acc[8];
        #pragma unroll
        for (int f = 0; f < 8; f++) acc[f] = (floatx4){0.f, 0.f, 0.f, 0.f};

        __syncthreads();

        // ---- MLP1: K = 320 (304 real + 16 zero-pad), 10 steps of 32 ----
        for (int s = 0; s < 10; s++) {
            const int k0 = s * 32;
            // A stage: thread -> (edge = tid>>2, kq = (tid&3)*8)
            {
                const int e  = tid >> 2;
                const int kq = (tid & 3) * 8;
                const int k  = k0 + kq;
                float v[8];
                if (k < 128) {
                    const float4* p = (const float4*)&h[sSrc[e] * H + k];
                    float4 a = p[0], b = p[1];
                    v[0]=a.x; v[1]=a.y; v[2]=a.z; v[3]=a.w;
                    v[4]=b.x; v[5]=b.y; v[6]=b.z; v[7]=b.w;
                } else if (k < 256) {
                    int dd = sDst[e]; dd = dd < 0 ? 0 : dd;
                    const float4* p = (const float4*)&h[dd * H + (k - 128)];
                    float4 a = p[0], b = p[1];
                    v[0]=a.x; v[1]=a.y; v[2]=a.z; v[3]=a.w;
                    v[4]=b.x; v[5]=b.y; v[6]=b.z; v[7]=b.w;
                } else if (k < 304) {
                    const int r = k - 256;
                    const float* p;
                    if (r < 16)      p = &sRelE[sRel[e] * 16 + r];
                    else if (r < 24) p = &sRoleE[sRS[e] * 8 + (r - 16)];
                    else if (r < 32) p = &sRoleE[sRD[e] * 8 + (r - 24)];
                    else if (r < 40) p = &sColE[sCS[e] * 8 + (r - 32)];
                    else             p = &sColE[sCD[e] * 8 + (r - 40)];
                    #pragma unroll
                    for (int j = 0; j < 8; j++) v[j] = p[j];
                } else {
                    #pragma unroll
                    for (int j = 0; j < 8; j++) v[j] = 0.0f;
                }
                half8 o;
                #pragma unroll
                for (int j = 0; j < 8; j++) o[j] = (_Float16)v[j];
                *(half8*)&sA[e * 40 + kq] = o;
            }
            // B stage: thread -> (n = tid&127, kh = (tid>>7)*16); transposed
            {
                const int n  = tid & 127;
                const int kh = (tid >> 7) * 16;
                #pragma unroll
                for (int i = 0; i < 16; i += 2) {
                    const int ka = k0 + kh + i;
                    const int kb = ka + 1;
                    float wa = (ka < 304) ? eW1[ka * H + n] : 0.0f;
                    float wb = (kb < 304) ? eW1[kb * H + n] : 0.0f;
                    union { _Float16 f[2]; unsigned u; } pk;
                    pk.f[0] = (_Float16)wa; pk.f[1] = (_Float16)wb;
                    *(unsigned*)&sB[n * 40 + kh + i] = pk.u;
                }
            }
            __syncthreads();
            half8 af = *(const half8*)&sA[(wv * 16 + lm) * 40 + lh * 8];
            #pragma unroll
            for (int f = 0; f < 8; f++) {
                half8 bf = *(const half8*)&sB[(f * 16 + lm) * 40 + lh * 8];
                acc[f] = __builtin_amdgcn_mfma_f32_16x16x32_f16(af, bf, acc[f], 0, 0, 0);
            }
            __syncthreads();
        }

        // y = silu(acc + eb1) -> sY  (C layout: col = lm, row = lh*4+v)
        #pragma unroll
        for (int f = 0; f < 8; f++) {
            const int col = f * 16 + lm;
            const float b1 = eb1[col];
            #pragma unroll
            for (int v = 0; v < 4; v++) {
                const int row = wv * 16 + lh * 4 + v;
                sY[row * 136 + col] = (_Float16)silu_f(acc[f][v] + b1);
            }
        }

        floatx4 acc2[8];
        #pragma unroll
        for (int f = 0; f < 8; f++) acc2[f] = (floatx4){0.f, 0.f, 0.f, 0.f};

        __syncthreads();

        // ---- MLP2: K = 128, 4 steps ----
        for (int s2 = 0; s2 < 4; s2++) {
            {
                const int n  = tid & 127;
                const int kh = (tid >> 7) * 16;
                #pragma unroll
                for (int i = 0; i < 16; i += 2) {
                    const int ka = s2 * 32 + kh + i;
                    float wa = eW2[ka * H + n];
                    float wb = eW2[(ka + 1) * H + n];
                    union { _Float16 f[2]; unsigned u; } pk;
                    pk.f[0] = (_Float16)wa; pk.f[1] = (_Float16)wb;
                    *(unsigned*)&sB[n * 40 + kh + i] = pk.u;
                }
            }
            __syncthreads();
            half8 af = *(const half8*)&sY[(wv * 16 + lm) * 136 + s2 * 32 + lh * 8];
            #pragma unroll
            for (int f = 0; f < 8; f++) {
                half8 bf = *(const half8*)&sB[(f * 16 + lm) * 40 + lh * 8];
                acc2[f] = __builtin_amdgcn_mfma_f32_16x16x32_f16(af, bf, acc2[f], 0, 0, 0);
            }
            __syncthreads();
        }

        // message = silu(acc2 + eb2); bucketed scatter-add
        #pragma unroll
        for (int f = 0; f < 8; f++) {
            const int col = f * 16 + lm;
            const float b2 = eb2[col];
            #pragma unroll
            for (int v = 0; v < 4; v++) {
                const int row = wv * 16 + lh * 4 + v;
                const int d = sDst[row];
                if (d >= 0)
                    unsafeAtomicAdd(&agg[d * H + col], silu_f(acc2[f][v] + b2));
            }
        }
    }
}

// ---------------------------------------------------------------------------
// Node kernel (fp16 MFMA): [h | agg | role | color] (272, pad 288) -> MLP1
// -> silu -> MLP2 -> +h -> LayerNorm -> out.
// ---------------------------------------------------------------------------
__global__ void __launch_bounds__(256)
node_mfma(const float* __restrict__ h, const float* __restrict__ agg,
          const int* __restrict__ ncol, const int* __restrict__ nrole,
          const float* __restrict__ role_emb, const float* __restrict__ col_emb,
          const float* __restrict__ nW1, const float* __restrict__ nb1,
          const float* __restrict__ nW2, const float* __restrict__ nb2,
          const float* __restrict__ ln_g, const float* __restrict__ ln_b,
          float* __restrict__ out, int N)
{
    __shared__ _Float16 sA[64 * 40];
    __shared__ _Float16 sB[128 * 40];
    __shared__ _Float16 sY[64 * 136];
    __shared__ int sRole[64], sCol[64];
    __shared__ float sRoleE[48], sColE[24];

    const int tid  = threadIdx.x;
    const int lane = tid & 63;
    const int wv   = tid >> 6;
    const int lm   = lane & 15;
    const int lh   = lane >> 4;
    const int n0   = blockIdx.x * 64;

    if (tid < 48) sRoleE[tid] = role_emb[tid];
    if (tid < 24) sColE[tid] = col_emb[tid];
    if (tid < 64) {
        int n = n0 + tid; if (n >= N) n = N - 1;
        sRole[tid] = nrole[n];
        sCol[tid]  = ncol[n];
    }

    floatx4 acc[8];
    #pragma unroll
    for (int f = 0; f < 8; f++) acc[f] = (floatx4){0.f, 0.f, 0.f, 0.f};

    __syncthreads();

    // ---- MLP1: K = 288 (272 real), 9 steps ----
    for (int s = 0; s < 9; s++) {
        const int k0 = s * 32;
        {
            const int r  = tid >> 2;
            const int kq = (tid & 3) * 8;
            const int k  = k0 + kq;
            int n = n0 + r; if (n >= N) n = N - 1;
            float v[8];
            if (k < 128) {
                const float4* p = (const float4*)&h[n * H + k];
                float4 a = p[0], b = p[1];
                v[0]=a.x; v[1]=a.y; v[2]=a.z; v[3]=a.w;
                v[4]=b.x; v[5]=b.y; v[6]=b.z; v[7]=b.w;
            } else if (k < 256) {
                const float4* p = (const float4*)&agg[n * H + (k - 128)];
                float4 a = p[0], b = p[1];
                v[0]=a.x; v[1]=a.y; v[2]=a.z; v[3]=a.w;
                v[4]=b.x; v[5]=b.y; v[6]=b.z; v[7]=b.w;
            } else if (k < 264) {
                const float* p = &sRoleE[sRole[r] * 8 + (k - 256)];
                #pragma unroll
                for (int j = 0; j < 8; j++) v[j] = p[j];
            } else if (k < 272) {
                const float* p = &sColE[sCol[r] * 8 + (k - 264)];
                #pragma unroll
                for (int j = 0; j < 8; j++) v[j] = p[j];
            } else {
                #pragma unroll
                for (int j = 0; j < 8; j++) v[j] = 0.0f;
            }
            half8 o;
            #pragma unroll
            for (int j = 0; j < 8; j++) o[j] = (_Float16)v[j];
            *(half8*)&sA[r * 40 + kq] = o;
        }
        {
            const int n  = tid & 127;
            const int kh = (tid >> 7) * 16;
            #pragma unroll
            for (int i = 0; i < 16; i += 2) {
                const int ka = k0 + kh + i;
                const int kb = ka + 1;
                float wa = (ka < 272) ? nW1[ka * H + n] : 0.0f;
                float wb = (kb < 272) ? nW1[kb * H + n] : 0.0f;
                union { _Float16 f[2]; unsigned u; } pk;
                pk.f[0] = (_Float16)wa; pk.f[1] = (_Float16)wb;
                *(unsigned*)&sB[n * 40 + kh + i] = pk.u;
            }
        }
        __syncthreads();
        half8 af = *(const half8*)&sA[(wv * 16 + lm) * 40 + lh * 8];
        #pragma unroll
        for (int f = 0; f < 8; f++) {
            half8 bf = *(const half8*)&sB[(f * 16 + lm) * 40 + lh * 8];
            acc[f] = __builtin_amdgcn_mfma_f32_16x16x32_f16(af, bf, acc[f], 0, 0, 0);
        }
        __syncthreads();
    }

    #pragma unroll
    for (int f = 0; f < 8; f++) {
        const int col = f * 16 + lm;
        const float b1 = nb1[col];
        #pragma unroll
        for (int v = 0; v < 4; v++) {
            const int row = wv * 16 + lh * 4 + v;
            sY[row * 136 + col] = (_Float16)silu_f(acc[f][v] + b1);
        }
    }

    floatx4 acc2[8];
    #pragma unroll
    for (int f = 0; f < 8; f++) acc2[f] = (floatx4){0.f, 0.f, 0.f, 0.f};

    __syncthreads();

    // ---- MLP2: K = 128, 4 steps ----
    for (int s2 = 0; s2 < 4; s2++) {
        {
            const int n  = tid & 127;
            const int kh = (tid >> 7) * 16;
            #pragma unroll
            for (int i = 0; i < 16; i += 2) {
                const int ka = s2 * 32 + kh + i;
                float wa = nW2[ka * H + n];
                float wb = nW2[(ka + 1) * H + n];
                union { _Float16 f[2]; unsigned u; } pk;
                pk.f[0] = (_Float16)wa; pk.f[1] = (_Float16)wb;
                *(unsigned*)&sB[n * 40 + kh + i] = pk.u;
            }
        }
        __syncthreads();
        half8 af = *(const half8*)&sY[(wv * 16 + lm) * 136 + s2 * 32 + lh * 8];
        #pragma unroll
        for (int f = 0; f < 8; f++) {
            half8 bf = *(const half8*)&sB[(f * 16 + lm) * 40 + lh * 8];
            acc2[f] = __builtin_amdgcn_mfma_f32_16x16x32_f16(af, bf, acc2[f], 0, 0, 0);
        }
        __syncthreads();
    }

    // residual + LayerNorm + store
    float g[8], bb[8], b2[8];
    #pragma unroll
    for (int f = 0; f < 8; f++) {
        const int col = f * 16 + lm;
        g[f]  = ln_g[col];
        bb[f] = ln_b[col];
        b2[f] = nb2[col];
    }
    #pragma unroll
    for (int v = 0; v < 4; v++) {
        const int row = n0 + wv * 16 + lh * 4 + v;
        const int rc  = row < N ? row : N - 1;
        float x[8];
        float sum = 0.0f;
        #pragma unroll
        for (int f = 0; f < 8; f++) {
            const int col = f * 16 + lm;
            x[f] = h[rc * H + col] + acc2[f][v] + b2[f];
            sum += x[f];
        }
        sum += __shfl_xor(sum, 1);
        sum += __shfl_xor(sum, 2);
        sum += __shfl_xor(sum, 4);
        sum += __shfl_xor(sum, 8);
        const float mu = sum * (1.0f / 128.0f);
        float vs = 0.0f;
        #pragma unroll
        for (int f = 0; f < 8; f++) { float dx = x[f] - mu; vs += dx * dx; }
        vs += __shfl_xor(vs, 1);
        vs += __shfl_xor(vs, 2);
        vs += __shfl_xor(vs, 4);
        vs += __shfl_xor(vs, 8);
        const float rstd = rsqrtf(vs * (1.0f / 128.0f) + LN_EPS);
        if (row < N) {
            #pragma unroll
            for (int f = 0; f < 8; f++) {
                const int col = f * 16 + lm;
                out[row * H + col] = (x[f] - mu) * rstd * g[f] + bb[f];
            }
        }
    }
}

extern "C" void kernel_launch(void* const* d_in, const int* in_sizes, int n_in,
                              void* d_out, int out_size, void* d_ws, size_t ws_size,
                              hipStream_t stream)
{
    const float* h        = (const float*)d_in[0];
    const int*   eidx     = (const int*)d_in[1];
    const int*   erel     = (const int*)d_in[2];
    const int*   ncol     = (const int*)d_in[3];
    const int*   nrole    = (const int*)d_in[4];
    const float* rel_emb  = (const float*)d_in[5];
    const float* role_emb = (const float*)d_in[6];
    const float* col_emb  = (const float*)d_in[7];
    const float* eW1      = (const float*)d_in[8];
    const float* eb1      = (const float*)d_in[9];
    const float* eW2      = (const float*)d_in[10];
    const float* eb2      = (const float*)d_in[11];
    const float* nW1      = (const float*)d_in[12];
    const float* nb1      = (const float*)d_in[13];
    const float* nW2      = (const float*)d_in[14];
    const float* nb2      = (const float*)d_in[15];
    const float* ln_g     = (const float*)d_in[16];
    const float* ln_b     = (const float*)d_in[17];

    const int N = in_sizes[0] / H;
    const int E = in_sizes[2];
    const int* esrc = eidx;
    const int* edst = eidx + E;
    const int bsz = (N + 7) / 8;

    float* agg = (float*)d_ws;               // N*H fp32 scratch
    int* perm  = (int*)d_out;                // reuse output buffer as sort scratch
    int* cnt   = perm + E;                   // cnt[8] | base[8] | cursor[8]

    hipMemsetAsync(agg, 0, (size_t)N * H * sizeof(float), stream);
    hipMemsetAsync(cnt, 0, 24 * sizeof(int), stream);

    hist_kernel<<<512, 256, 0, stream>>>(edst, E, bsz, cnt);
    prefix_kernel<<<1, 64, 0, stream>>>(cnt);
    scatter_kernel<<<512, 256, 0, stream>>>(edst, E, bsz, cnt + 16, perm);

    dim3 egrid(8, 256);
    edge_mfma<<<egrid, 256, 0, stream>>>(
        h, perm, cnt, esrc, edst, erel, ncol, nrole,
        rel_emb, role_emb, col_emb, eW1, eb1, eW2, eb2, agg);

    node_mfma<<<(N + 63) / 64, 256, 0, stream>>>(
        h, agg, ncol, nrole, role_emb, col_emb,
        nW1, nb1, nW2, nb2, ln_g, ln_b, (float*)d_out, N);
}

// Round 7
// 724.104 us; speedup vs baseline: 4.2703x; 4.2703x over previous
//
#include <hip/hip_runtime.h>

#define H 128
#define LN_EPS 1e-5f
#define SNB 256   // sort blocks
#define SNT 256   // sort threads/block

typedef _Float16 half8 __attribute__((ext_vector_type(8)));
typedef float floatx4 __attribute__((ext_vector_type(4)));

__device__ __forceinline__ float silu_f(float x) { return x / (1.0f + __expf(-x)); }

// ---------------------------------------------------------------------------
// fp32 -> fp16 converters (one-time per launch)
// ---------------------------------------------------------------------------
__global__ void cvt_h16(const float* __restrict__ src, _Float16* __restrict__ dst,
                        int total8)
{
    int i = blockIdx.x * blockDim.x + threadIdx.x;
    if (i >= total8) return;
    const float4* p = (const float4*)(src + i * 8);
    float4 a = p[0], b = p[1];
    half8 o;
    o[0] = (_Float16)a.x; o[1] = (_Float16)a.y; o[2] = (_Float16)a.z; o[3] = (_Float16)a.w;
    o[4] = (_Float16)b.x; o[5] = (_Float16)b.y; o[6] = (_Float16)b.z; o[7] = (_Float16)b.w;
    *(half8*)(dst + i * 8) = o;
}

// W [K][128] fp32 -> WT [128][Kpad] fp16 (zero-padded K..Kpad)
__global__ void cvt_wT(const float* __restrict__ W, _Float16* __restrict__ WT,
                       int K, int Kpad)
{
    int i = blockIdx.x * blockDim.x + threadIdx.x;
    if (i >= 128 * Kpad) return;
    int n = i / Kpad, k = i - n * Kpad;
    WT[i] = (k < K) ? (_Float16)W[k * H + n] : (_Float16)0.0f;
}

// ---------------------------------------------------------------------------
// Contention-free counting sort into 8 dst-buckets.
// gcnt/gbase layout: [bucket][block]  (bucket-major)
// ---------------------------------------------------------------------------
__global__ void hist_kernel(const int* __restrict__ edst, int E, int bsz,
                            int* __restrict__ gcnt)
{
    __shared__ int lc[8];
    if (threadIdx.x < 8) lc[threadIdx.x] = 0;
    __syncthreads();
    for (int e = blockIdx.x * SNT + threadIdx.x; e < E; e += SNB * SNT)
        atomicAdd(&lc[edst[e] / bsz], 1);
    __syncthreads();
    if (threadIdx.x < 8) gcnt[threadIdx.x * SNB + blockIdx.x] = lc[threadIdx.x];
}

__global__ void scan_kernel(const int* __restrict__ gcnt, int* __restrict__ gbase,
                            int* __restrict__ binfo)
{
    __shared__ int v[8 * SNB];
    for (int i = threadIdx.x; i < 8 * SNB; i += blockDim.x) v[i] = gcnt[i];
    __syncthreads();
    if (threadIdx.x == 0) {
        int s = 0;
        for (int b = 0; b < 8; b++) {
            binfo[8 + b] = s;                    // bucket base
            for (int j = 0; j < SNB; j++) {
                int c = v[b * SNB + j];
                v[b * SNB + j] = s;
                s += c;
            }
            binfo[b] = s - binfo[8 + b];         // bucket count
        }
    }
    __syncthreads();
    for (int i = threadIdx.x; i < 8 * SNB; i += blockDim.x) gbase[i] = v[i];
}

__global__ void scatter_kernel(const int* __restrict__ edst, int E, int bsz,
                               const int* __restrict__ gbase, int* __restrict__ perm)
{
    __shared__ int cur[8];
    if (threadIdx.x < 8) cur[threadIdx.x] = gbase[threadIdx.x * SNB + blockIdx.x];
    __syncthreads();
    for (int e = blockIdx.x * SNT + threadIdx.x; e < E; e += SNB * SNT) {
        int b = edst[e] / bsz;
        int p = atomicAdd(&cur[b], 1);
        perm[p] = e;
    }
}

// ---------------------------------------------------------------------------
// Edge kernel (fp16 MFMA): grid (8 buckets, GY). Block = 256 thr = 4 waves,
// tile = 64 edges x 128 out. B fragments read directly from fp16 transposed
// weight tables (L1/L2-resident). Double-buffered sA, one barrier per K-step.
// ---------------------------------------------------------------------------
__global__ void __launch_bounds__(256)
edge_mfma(const _Float16* __restrict__ h16,
          const int* __restrict__ perm, const int* __restrict__ binfo,
          const int* __restrict__ esrc, const int* __restrict__ edst,
          const int* __restrict__ erel, const int* __restrict__ ncol,
          const int* __restrict__ nrole,
          const float* __restrict__ rel_emb, const float* __restrict__ role_emb,
          const float* __restrict__ col_emb,
          const _Float16* __restrict__ w1t,   // [128][320]
          const float* __restrict__ eb1,
          const _Float16* __restrict__ w2t,   // [128][128]
          const float* __restrict__ eb2,
          float* __restrict__ agg)
{
    __shared__ _Float16 sA[2][64 * 40];   // [edge][k-slice 32], stride 40
    __shared__ _Float16 sY[64 * 136];     // [edge][128], stride 136
    __shared__ int sSrc[64], sDst[64], sRel[64], sRS[64], sRD[64], sCS[64], sCD[64];
    __shared__ float sRelE[128], sRoleE[48], sColE[24];

    const int tid  = threadIdx.x;
    const int lane = tid & 63;
    const int wv   = tid >> 6;
    const int lm   = lane & 15;
    const int lh   = lane >> 4;

    if (tid < 128) sRelE[tid] = rel_emb[tid];
    if (tid < 48)  sRoleE[tid] = role_emb[tid];
    if (tid < 24)  sColE[tid] = col_emb[tid];

    const int bucket = blockIdx.x;
    const int bcount = binfo[bucket];
    const int bbase  = binfo[8 + bucket];

    // A-stage thread mapping: edge = tid>>2, k-quad = (tid&3)*8
    const int ae = tid >> 2;
    const int akq = (tid & 3) * 8;

    for (int t = blockIdx.y; t * 64 < bcount; t += gridDim.y)
    {
        __syncthreads();   // protect previous tile's LDS

        if (tid < 64) {
            int idx   = t * 64 + tid;
            int valid = idx < bcount;
            int e = valid ? perm[bbase + idx] : perm[bbase];
            int s = esrc[e], d = edst[e], r = erel[e];
            sSrc[tid] = s; sRel[tid] = r;
            sRS[tid]  = nrole[s]; sRD[tid] = nrole[d];
            sCS[tid]  = ncol[s];  sCD[tid] = ncol[d];
            sDst[tid] = valid ? d : -1;
        }

        floatx4 acc[8];
        #pragma unroll
        for (int f = 0; f < 8; f++) acc[f] = (floatx4){0.f, 0.f, 0.f, 0.f};

        __syncthreads();

        // ---- stage A for K-step 0 ----
        {
            const int k = akq;   // step 0: k < 128 always
            half8 o = *(const half8*)&h16[sSrc[ae] * H + k];
            *(half8*)&sA[0][ae * 40 + akq] = o;
        }

        // ---- MLP1: K = 320 (304 real), 10 steps of 32, A double-buffered ----
        for (int s = 0; s < 10; s++) {
            __syncthreads();
            if (s < 9) {
                const int k = (s + 1) * 32 + akq;
                half8 o;
                if (k < 128) {
                    o = *(const half8*)&h16[sSrc[ae] * H + k];
                } else if (k < 256) {
                    int dd = sDst[ae]; dd = dd < 0 ? 0 : dd;
                    o = *(const half8*)&h16[dd * H + (k - 128)];
                } else if (k < 304) {
                    const int r = k - 256;
                    const float* p;
                    if (r < 16)      p = &sRelE[sRel[ae] * 16 + r];
                    else if (r < 24) p = &sRoleE[sRS[ae] * 8 + (r - 16)];
                    else if (r < 32) p = &sRoleE[sRD[ae] * 8 + (r - 24)];
                    else if (r < 40) p = &sColE[sCS[ae] * 8 + (r - 32)];
                    else             p = &sColE[sCD[ae] * 8 + (r - 40)];
                    #pragma unroll
                    for (int j = 0; j < 8; j++) o[j] = (_Float16)p[j];
                } else {
                    #pragma unroll
                    for (int j = 0; j < 8; j++) o[j] = (_Float16)0.0f;
                }
                *(half8*)&sA[(s + 1) & 1][ae * 40 + akq] = o;
            }
            half8 af = *(const half8*)&sA[s & 1][(wv * 16 + lm) * 40 + lh * 8];
            const int kb = s * 32 + lh * 8;
            #pragma unroll
            for (int f = 0; f < 8; f++) {
                half8 bf = *(const half8*)&w1t[(f * 16 + lm) * 320 + kb];
                acc[f] = __builtin_amdgcn_mfma_f32_16x16x32_f16(af, bf, acc[f], 0, 0, 0);
            }
        }

        // y = silu(acc + eb1) -> sY  (C layout: col = lm, row = lh*4+v)
        #pragma unroll
        for (int f = 0; f < 8; f++) {
            const int col = f * 16 + lm;
            const float b1 = eb1[col];
            #pragma unroll
            for (int v = 0; v < 4; v++) {
                const int row = wv * 16 + lh * 4 + v;
                sY[row * 136 + col] = (_Float16)silu_f(acc[f][v] + b1);
            }
        }

        floatx4 acc2[8];
        #pragma unroll
        for (int f = 0; f < 8; f++) acc2[f] = (floatx4){0.f, 0.f, 0.f, 0.f};

        __syncthreads();

        // ---- MLP2: K = 128, 4 steps, B direct from w2t ----
        #pragma unroll
        for (int s2 = 0; s2 < 4; s2++) {
            half8 af = *(const half8*)&sY[(wv * 16 + lm) * 136 + s2 * 32 + lh * 8];
            const int kb = s2 * 32 + lh * 8;
            #pragma unroll
            for (int f = 0; f < 8; f++) {
                half8 bf = *(const half8*)&w2t[(f * 16 + lm) * 128 + kb];
                acc2[f] = __builtin_amdgcn_mfma_f32_16x16x32_f16(af, bf, acc2[f], 0, 0, 0);
            }
        }

        // message = silu(acc2 + eb2); bucketed scatter-add
        #pragma unroll
        for (int f = 0; f < 8; f++) {
            const int col = f * 16 + lm;
            const float b2 = eb2[col];
            #pragma unroll
            for (int v = 0; v < 4; v++) {
                const int row = wv * 16 + lh * 4 + v;
                const int d = sDst[row];
                if (d >= 0)
                    unsafeAtomicAdd(&agg[d * H + col], silu_f(acc2[f][v] + b2));
            }
        }
    }
}

// ---------------------------------------------------------------------------
// Node kernel (fp16 MFMA): [h | agg | role | color] (272, pad 288) -> MLP1
// -> silu -> MLP2 -> +h -> LayerNorm -> out.  (Unchanged staging path.)
// ---------------------------------------------------------------------------
__global__ void __launch_bounds__(256)
node_mfma(const float* __restrict__ h, const float* __restrict__ agg,
          const int* __restrict__ ncol, const int* __restrict__ nrole,
          const float* __restrict__ role_emb, const float* __restrict__ col_emb,
          const float* __restrict__ nW1, const float* __restrict__ nb1,
          const float* __restrict__ nW2, const float* __restrict__ nb2,
          const float* __restrict__ ln_g, const float* __restrict__ ln_b,
          float* __restrict__ out, int N)
{
    __shared__ _Float16 sA[64 * 40];
    __shared__ _Float16 sB[128 * 40];
    __shared__ _Float16 sY[64 * 136];
    __shared__ int sRole[64], sCol[64];
    __shared__ float sRoleE[48], sColE[24];

    const int tid  = threadIdx.x;
    const int lane = tid & 63;
    const int wv   = tid >> 6;
    const int lm   = lane & 15;
    const int lh   = lane >> 4;
    const int n0   = blockIdx.x * 64;

    if (tid < 48) sRoleE[tid] = role_emb[tid];
    if (tid < 24) sColE[tid] = col_emb[tid];
    if (tid < 64) {
        int n = n0 + tid; if (n >= N) n = N - 1;
        sRole[tid] = nrole[n];
        sCol[tid]  = ncol[n];
    }

    floatx4 acc[8];
    #pragma unroll
    for (int f = 0; f < 8; f++) acc[f] = (floatx4){0.f, 0.f, 0.f, 0.f};

    __syncthreads();

    // ---- MLP1: K = 288 (272 real), 9 steps ----
    for (int s = 0; s < 9; s++) {
        const int k0 = s * 32;
        {
            const int r  = tid >> 2;
            const int kq = (tid & 3) * 8;
            const int k  = k0 + kq;
            int n = n0 + r; if (n >= N) n = N - 1;
            float v[8];
            if (k < 128) {
                const float4* p = (const float4*)&h[n * H + k];
                float4 a = p[0], b = p[1];
                v[0]=a.x; v[1]=a.y; v[2]=a.z; v[3]=a.w;
                v[4]=b.x; v[5]=b.y; v[6]=b.z; v[7]=b.w;
            } else if (k < 256) {
                const float4* p = (const float4*)&agg[n * H + (k - 128)];
                float4 a = p[0], b = p[1];
                v[0]=a.x; v[1]=a.y; v[2]=a.z; v[3]=a.w;
                v[4]=b.x; v[5]=b.y; v[6]=b.z; v[7]=b.w;
            } else if (k < 264) {
                const float* p = &sRoleE[sRole[r] * 8 + (k - 256)];
                #pragma unroll
                for (int j = 0; j < 8; j++) v[j] = p[j];
            } else if (k < 272) {
                const float* p = &sColE[sCol[r] * 8 + (k - 264)];
                #pragma unroll
                for (int j = 0; j < 8; j++) v[j] = p[j];
            } else {
                #pragma unroll
                for (int j = 0; j < 8; j++) v[j] = 0.0f;
            }
            half8 o;
            #pragma unroll
            for (int j = 0; j < 8; j++) o[j] = (_Float16)v[j];
            *(half8*)&sA[r * 40 + kq] = o;
        }
        {
            const int n  = tid & 127;
            const int kh = (tid >> 7) * 16;
            #pragma unroll
            for (int i = 0; i < 16; i += 2) {
                const int ka = k0 + kh + i;
                const int kb = ka + 1;
                float wa = (ka < 272) ? nW1[ka * H + n] : 0.0f;
                float wb = (kb < 272) ? nW1[kb * H + n] : 0.0f;
                union { _Float16 f[2]; unsigned u; } pk;
                pk.f[0] = (_Float16)wa; pk.f[1] = (_Float16)wb;
                *(unsigned*)&sB[n * 40 + kh + i] = pk.u;
            }
        }
        __syncthreads();
        half8 af = *(const half8*)&sA[(wv * 16 + lm) * 40 + lh * 8];
        #pragma unroll
        for (int f = 0; f < 8; f++) {
            half8 bf = *(const half8*)&sB[(f * 16 + lm) * 40 + lh * 8];
            acc[f] = __builtin_amdgcn_mfma_f32_16x16x32_f16(af, bf, acc[f], 0, 0, 0);
        }
        __syncthreads();
    }

    #pragma unroll
    for (int f = 0; f < 8; f++) {
        const int col = f * 16 + lm;
        const float b1 = nb1[col];
        #pragma unroll
        for (int v = 0; v < 4; v++) {
            const int row = wv * 16 + lh * 4 + v;
            sY[row * 136 + col] = (_Float16)silu_f(acc[f][v] + b1);
        }
    }

    floatx4 acc2[8];
    #pragma unroll
    for (int f = 0; f < 8; f++) acc2[f] = (floatx4){0.f, 0.f, 0.f, 0.f};

    __syncthreads();

    // ---- MLP2: K = 128, 4 steps ----
    for (int s2 = 0; s2 < 4; s2++) {
        {
            const int n  = tid & 127;
            const int kh = (tid >> 7) * 16;
            #pragma unroll
            for (int i = 0; i < 16; i += 2) {
                const int ka = s2 * 32 + kh + i;
                float wa = nW2[ka * H + n];
                float wb = nW2[(ka + 1) * H + n];
                union { _Float16 f[2]; unsigned u; } pk;
                pk.f[0] = (_Float16)wa; pk.f[1] = (_Float16)wb;
                *(unsigned*)&sB[n * 40 + kh + i] = pk.u;
            }
        }
        __syncthreads();
        half8 af = *(const half8*)&sY[(wv * 16 + lm) * 136 + s2 * 32 + lh * 8];
        #pragma unroll
        for (int f = 0; f < 8; f++) {
            half8 bf = *(const half8*)&sB[(f * 16 + lm) * 40 + lh * 8];
            acc2[f] = __builtin_amdgcn_mfma_f32_16x16x32_f16(af, bf, acc2[f], 0, 0, 0);
        }
        __syncthreads();
    }

    // residual + LayerNorm + store
    float g[8], bb[8], b2[8];
    #pragma unroll
    for (int f = 0; f < 8; f++) {
        const int col = f * 16 + lm;
        g[f]  = ln_g[col];
        bb[f] = ln_b[col];
        b2[f] = nb2[col];
    }
    #pragma unroll
    for (int v = 0; v < 4; v++) {
        const int row = n0 + wv * 16 + lh * 4 + v;
        const int rc  = row < N ? row : N - 1;
        float x[8];
        float sum = 0.0f;
        #pragma unroll
        for (int f = 0; f < 8; f++) {
            const int col = f * 16 + lm;
            x[f] = h[rc * H + col] + acc2[f][v] + b2[f];
            sum += x[f];
        }
        sum += __shfl_xor(sum, 1);
        sum += __shfl_xor(sum, 2);
        sum += __shfl_xor(sum, 4);
        sum += __shfl_xor(sum, 8);
        const float mu = sum * (1.0f / 128.0f);
        float vs = 0.0f;
        #pragma unroll
        for (int f = 0; f < 8; f++) { float dx = x[f] - mu; vs += dx * dx; }
        vs += __shfl_xor(vs, 1);
        vs += __shfl_xor(vs, 2);
        vs += __shfl_xor(vs, 4);
        vs += __shfl_xor(vs, 8);
        const float rstd = rsqrtf(vs * (1.0f / 128.0f) + LN_EPS);
        if (row < N) {
            #pragma unroll
            for (int f = 0; f < 8; f++) {
                const int col = f * 16 + lm;
                out[row * H + col] = (x[f] - mu) * rstd * g[f] + bb[f];
            }
        }
    }
}

extern "C" void kernel_launch(void* const* d_in, const int* in_sizes, int n_in,
                              void* d_out, int out_size, void* d_ws, size_t ws_size,
                              hipStream_t stream)
{
    const float* h        = (const float*)d_in[0];
    const int*   eidx     = (const int*)d_in[1];
    const int*   erel     = (const int*)d_in[2];
    const int*   ncol     = (const int*)d_in[3];
    const int*   nrole    = (const int*)d_in[4];
    const float* rel_emb  = (const float*)d_in[5];
    const float* role_emb = (const float*)d_in[6];
    const float* col_emb  = (const float*)d_in[7];
    const float* eW1      = (const float*)d_in[8];
    const float* eb1      = (const float*)d_in[9];
    const float* eW2      = (const float*)d_in[10];
    const float* eb2      = (const float*)d_in[11];
    const float* nW1      = (const float*)d_in[12];
    const float* nb1      = (const float*)d_in[13];
    const float* nW2      = (const float*)d_in[14];
    const float* nb2      = (const float*)d_in[15];
    const float* ln_g     = (const float*)d_in[16];
    const float* ln_b     = (const float*)d_in[17];

    const int N = in_sizes[0] / H;
    const int E = in_sizes[2];
    const int* esrc = eidx;
    const int* edst = eidx + E;
    const int bsz = (N + 7) / 8;

    float* agg = (float*)d_ws;                    // N*H fp32 scratch

    // Scratch carved from d_out (all dead before node_mfma writes output):
    // perm[E] | gcnt[8*SNB] | gbase[8*SNB] | binfo[16] | h16 | w1te | w2te
    int* perm  = (int*)d_out;
    int* gcnt  = perm + E;
    int* gbase = gcnt + 8 * SNB;
    int* binfo = gbase + 8 * SNB;
    size_t io = (size_t)(E + 16 * SNB + 16);
    io = (io + 7) & ~(size_t)7;                   // 32B-align fp16 region
    _Float16* h16  = (_Float16*)(perm + io);
    _Float16* w1te = h16 + (size_t)N * H;         // [128][320]
    _Float16* w2te = w1te + 128 * 320;            // [128][128]

    hipMemsetAsync(agg, 0, (size_t)N * H * sizeof(float), stream);

    cvt_h16<<<(N * H / 8 + 255) / 256, 256, 0, stream>>>(h, h16, N * H / 8);
    cvt_wT<<<(128 * 320 + 255) / 256, 256, 0, stream>>>(eW1, w1te, 304, 320);
    cvt_wT<<<(128 * 128 + 255) / 256, 256, 0, stream>>>(eW2, w2te, 128, 128);

    hist_kernel<<<SNB, SNT, 0, stream>>>(edst, E, bsz, gcnt);
    scan_kernel<<<1, 256, 0, stream>>>(gcnt, gbase, binfo);
    scatter_kernel<<<SNB, SNT, 0, stream>>>(edst, E, bsz, gbase, perm);

    dim3 egrid(8, 256);
    edge_mfma<<<egrid, 256, 0, stream>>>(
        h16, perm, binfo, esrc, edst, erel, ncol, nrole,
        rel_emb, role_emb, col_emb, w1te, eb1, w2te, eb2, agg);

    node_mfma<<<(N + 63) / 64, 256, 0, stream>>>(
        h, agg, ncol, nrole, role_emb, col_emb,
        nW1, nb1, nW2, nb2, ln_g, ln_b, (float*)d_out, N);
}